// Round 12
// baseline (80.667 us; speedup 1.0000x reference)
//
#include <hip/hip_runtime.h>
#include <math.h>

// Problem constants (fixed by the reference: B=4, N=4096, D=3)
constexpr int B_  = 4;
constexpr int N_  = 4096;
constexpr int NV  = N_ * 3;      // 12288 flattened residual elements per (batch,dir)
constexpr int QPT = 8;           // queries per thread in the NN kernel
constexpr int TPB_TAIL = 1024;   // tail kernel block size

// float <-> monotonic uint key (order-preserving bijection on finite floats)
__device__ inline unsigned f2k(float f) {
    unsigned b = __float_as_uint(f);
    return b ^ ((unsigned)((int)b >> 31) | 0x80000000u);
}
__device__ inline float k2f(unsigned k) {
    unsigned b = (k & 0x80000000u) ? (k ^ 0x80000000u) : ~k;
    return __uint_as_float(b);
}

// ---------------------------------------------------------------------------
// Kernel 1: partial NN over a candidate chunk, 8 queries per thread.
// grid = (NCCH=64 cand chunks, 2 query chunks, 8 pairs) = 1024 blocks
//      = 4 blocks/CU = 16 waves/CU = 4 waves/SIMD  <- TLP to hide LDS latency.
// (R2 evidence: issue saturation needs >=4 waves/SIMD; R10/R11 at 2 waves/SIMD
//  ran ~30% issue efficiency regardless of source-level pinning.)
// __launch_bounds__(256,4): cap VGPR at 128 so the ~90-reg query tile fits
// while guaranteeing the 4-wave/SIMD occupancy.
// LDS candidates prescaled {-2bx,-2by,-2bz,|b|^2} -> d2 in 3 FMAs.
// Strict '<' keeps the FIRST minimal index (jnp.argmin tie-break).
// ---------------------------------------------------------------------------
template <int NCCH>
__global__ __launch_bounds__(256, 4) void nn_partial_kernel(const float* __restrict__ x,
                                                            const float* __restrict__ y,
                                                            float2* __restrict__ part) {
    constexpr int CCH = N_ / NCCH;
    __shared__ float4 s2[CCH];
    const int pair = blockIdx.z;
    const int b    = pair >> 1;
    const int dir  = pair & 1;              // 0: S1=x,S2=y ; 1: S1=y,S2=x
    const float* S1 = (dir == 0 ? x : y) + b * NV;
    const float* S2 = (dir == 0 ? y : x) + b * NV;
    const int cbase = blockIdx.x * CCH;

    if (threadIdx.x < CCH) {
        int j = threadIdx.x;
        float bx = S2[(cbase + j) * 3 + 0];
        float by = S2[(cbase + j) * 3 + 1];
        float bz = S2[(cbase + j) * 3 + 2];
        s2[j] = make_float4(-2.f * bx, -2.f * by, -2.f * bz,
                            bx * bx + by * by + bz * bz);
    }
    __syncthreads();

    // 8 contiguous queries per thread: 24 floats = 6 aligned float4 loads.
    const int q0 = blockIdx.y * 2048 + threadIdx.x * QPT;
    float ax[QPT], ay[QPT], az[QPT];
    {
        const float4* p4 = (const float4*)(S1 + q0 * 3);
        float4 v[6];
        #pragma unroll
        for (int i = 0; i < 6; ++i) v[i] = p4[i];
        const float* f = (const float*)v;
        #pragma unroll
        for (int k = 0; k < QPT; ++k) {
            ax[k] = f[k * 3 + 0]; ay[k] = f[k * 3 + 1]; az[k] = f[k * 3 + 2];
        }
    }

    float bd[QPT]; int idx[QPT];
    #pragma unroll
    for (int k = 0; k < QPT; ++k) { bd[k] = INFINITY; idx[k] = 0; }

    #pragma unroll 4
    for (int j = 0; j < CCH; ++j) {
        float4 c = s2[j];                   // one ds_read_b128, broadcast
        const int jg = cbase + j;
        #pragma unroll
        for (int k = 0; k < QPT; ++k) {
            // d2 = |b|^2 - 2 a.b  (3 FMAs on prescaled candidate)
            float d2 = fmaf(ax[k], c.x, fmaf(ay[k], c.y, fmaf(az[k], c.z, c.w)));
            if (d2 < bd[k]) idx[k] = jg;    // v_cmp + v_cndmask
            bd[k] = fminf(d2, bd[k]);       // v_min
        }
    }

    float2 o[QPT];
    #pragma unroll
    for (int k = 0; k < QPT; ++k) o[k] = make_float2(bd[k], (float)idx[k]);
    float4* op = (float4*)(part + (size_t)(pair * NCCH + blockIdx.x) * N_ + q0);
    #pragma unroll
    for (int i = 0; i < QPT / 2; ++i) op[i] = ((const float4*)o)[i];
}

// ---------------------------------------------------------------------------
// Kernel 2: parallel merge. grid = (N_/256, 8 pairs), block = 256.
// NCCH fully unrolled -> independent dwordx2 loads (no latency chain),
// ascending chunk order + strict '<' == global first-index argmin.
// Writes monotonic keys component-major (keys[pair][comp*N+q]) -- fully
// coalesced; quantile/std are order-invariant over the flattened set.
// ---------------------------------------------------------------------------
template <int NCCH>
__global__ __launch_bounds__(256) void merge_keys_kernel(const float* __restrict__ x,
                                                         const float* __restrict__ y,
                                                         const float2* __restrict__ part,
                                                         unsigned* __restrict__ keys) {
    const int pair = blockIdx.y;
    const int b    = pair >> 1;
    const int dir  = pair & 1;
    const float* S1 = (dir == 0 ? x : y) + b * NV;
    const float* S2 = (dir == 0 ? y : x) + b * NV;
    const int q = blockIdx.x * 256 + threadIdx.x;

    float best = INFINITY;
    int bidx = 0;
    #pragma unroll
    for (int c = 0; c < NCCH; ++c) {
        float2 p = part[(size_t)(pair * NCCH + c) * N_ + q];
        if (p.x < best) { best = p.x; bidx = (int)p.y; }
    }
    unsigned* kp = keys + (size_t)pair * NV;
    kp[0 * N_ + q] = f2k(S1[q * 3 + 0] - S2[bidx * 3 + 0]);
    kp[1 * N_ + q] = f2k(S1[q * 3 + 1] - S2[bidx * 3 + 1]);
    kp[2 * N_ + q] = f2k(S1[q * 3 + 2] - S2[bidx * 3 + 2]);
}

// ---------------------------------------------------------------------------
// Kernel 3 (TAIL): one block per (batch,dir) pair, 1024 threads (16 waves).
//   A: stream keys into LDS (3 uint4 loads/thread, coalesced).
//   B: 4x 8-bit MSD radix-select for all four quantile order-stats at once
//      (uint4-vectorized scans; pass-1 hist has 8 wave-group-private copies).
//   C: fused count(<=key0)/min(>key0) -> linear-interp quantiles
//      (positions in fp32, identical to jnp.quantile).
//   D: two-pass masked mean/std from LDS keys (k2f exact inverse).
// ---------------------------------------------------------------------------
__global__ __launch_bounds__(TPB_TAIL) void tail_kernel(const unsigned* __restrict__ gkeys,
                                                        float* __restrict__ stats) {
    __shared__ unsigned keys[NV];           // 48 KB
    __shared__ int hist8[8][256];           // 8 KB
    __shared__ unsigned s_prefix[4];
    __shared__ int s_want[4];
    __shared__ int s_cnt[4];
    __shared__ unsigned s_mn[4];
    __shared__ float s_qv[4];
    __shared__ float red[64];
    __shared__ float sh[8];

    const int pair = blockIdx.x;
    const int tid  = threadIdx.x;
    const int lane = tid & 63;
    const int wid  = tid >> 6;              // 16 waves

    // ---- Phase A: stream keys into LDS ----
    const uint4* g4 = (const uint4*)(gkeys + (size_t)pair * NV);
    uint4* l4w = (uint4*)keys;
    #pragma unroll
    for (int i = 0; i < 3; ++i)             // NV/4 = 3072 = 3 * 1024 exact
        l4w[i * TPB_TAIL + tid] = g4[i * TPB_TAIL + tid];
    if (tid < 4) {
        const float Qs[4] = {0.05f, 0.95f, 0.25f, 0.75f};
        s_prefix[tid] = 0u;
        s_want[tid]   = (int)floorf(Qs[tid] * (float)(NV - 1));
    }
    __syncthreads();

    // ---- Phase B: 4 radix passes (uint4-vectorized element scans) ----
    const uint4* k4 = (const uint4*)keys;
    #pragma unroll 1
    for (int pass = 0; pass < 4; ++pass) {
        const int shift = 24 - 8 * pass;
        ((int*)hist8)[tid]             = 0; // 2048 ints, 2 stores/thread
        ((int*)hist8)[tid + TPB_TAIL]  = 0;
        __syncthreads();

        if (pass == 0) {
            int* h = hist8[wid & 7];        // wave-group-private copy
            for (int i = tid; i < NV / 4; i += TPB_TAIL) {
                uint4 kv = k4[i];
                atomicAdd(&h[kv.x >> 24], 1);
                atomicAdd(&h[kv.y >> 24], 1);
                atomicAdd(&h[kv.z >> 24], 1);
                atomicAdd(&h[kv.w >> 24], 1);
            }
        } else {
            const unsigned pmask = 0xFFFFFFFFu << (32 - 8 * pass);
            const unsigned pf0 = s_prefix[0], pf1 = s_prefix[1];
            const unsigned pf2 = s_prefix[2], pf3 = s_prefix[3];
            for (int i = tid; i < NV / 4; i += TPB_TAIL) {
                uint4 kv = k4[i];
                const unsigned ks[4] = {kv.x, kv.y, kv.z, kv.w};
                #pragma unroll
                for (int u = 0; u < 4; ++u) {
                    const unsigned k  = ks[u];
                    const unsigned kp = k & pmask;
                    const int bin = (int)((k >> shift) & 255u);
                    if (kp == pf0) atomicAdd(&hist8[0][bin], 1);
                    if (kp == pf1) atomicAdd(&hist8[1][bin], 1);
                    if (kp == pf2) atomicAdd(&hist8[2][bin], 1);
                    if (kp == pf3) atomicAdd(&hist8[3][bin], 1);
                }
            }
        }
        __syncthreads();

        // selection: wave t (t<4) scans quantile t's histogram
        if (wid < 4) {
            int c0 = 0, c1 = 0, c2 = 0, c3 = 0;
            if (pass == 0) {
                #pragma unroll
                for (int cp = 0; cp < 8; ++cp) {
                    c0 += hist8[cp][lane * 4 + 0]; c1 += hist8[cp][lane * 4 + 1];
                    c2 += hist8[cp][lane * 4 + 2]; c3 += hist8[cp][lane * 4 + 3];
                }
            } else {
                c0 = hist8[wid][lane * 4 + 0]; c1 = hist8[wid][lane * 4 + 1];
                c2 = hist8[wid][lane * 4 + 2]; c3 = hist8[wid][lane * 4 + 3];
            }
            const int want = s_want[wid];
            int s = c0 + c1 + c2 + c3;
            int pre = s;
            #pragma unroll
            for (int off = 1; off < 64; off <<= 1) {
                int u = __shfl_up(pre, off);
                if (lane >= off) pre += u;
            }
            const int excl = pre - s;
            const bool hit = (want >= excl) && (want < excl + s);
            unsigned long long m = __ballot(hit);
            const int hl = (int)(__ffsll(m) - 1);
            if (lane == hl) {
                int w = want - excl;
                int sel;
                if      (w < c0)           { sel = lane * 4 + 0; }
                else if (w < c0 + c1)      { sel = lane * 4 + 1; w -= c0; }
                else if (w < c0 + c1 + c2) { sel = lane * 4 + 2; w -= c0 + c1; }
                else                       { sel = lane * 4 + 3; w -= c0 + c1 + c2; }
                s_prefix[wid] |= ((unsigned)sel) << shift;
                s_want[wid] = w;
            }
        }
        __syncthreads();
    }

    // ---- Phase C: count(<=key0) and min(>key0) for all 4 quantiles ----
    if (tid < 4) { s_cnt[tid] = 0; s_mn[tid] = 0xFFFFFFFFu; }
    __syncthreads();
    const unsigned kq0 = s_prefix[0], kq1 = s_prefix[1];
    const unsigned kq2 = s_prefix[2], kq3 = s_prefix[3];
    int cnt0 = 0, cnt1 = 0, cnt2 = 0, cnt3 = 0;
    unsigned mn0 = 0xFFFFFFFFu, mn1 = 0xFFFFFFFFu, mn2 = 0xFFFFFFFFu, mn3 = 0xFFFFFFFFu;
    for (int i = tid; i < NV / 4; i += TPB_TAIL) {
        uint4 kv = k4[i];
        const unsigned ks[4] = {kv.x, kv.y, kv.z, kv.w};
        #pragma unroll
        for (int u = 0; u < 4; ++u) {
            const unsigned k = ks[u];
            if (k <= kq0) cnt0++; else if (k < mn0) mn0 = k;
            if (k <= kq1) cnt1++; else if (k < mn1) mn1 = k;
            if (k <= kq2) cnt2++; else if (k < mn2) mn2 = k;
            if (k <= kq3) cnt3++; else if (k < mn3) mn3 = k;
        }
    }
    #pragma unroll
    for (int off = 32; off > 0; off >>= 1) {
        cnt0 += __shfl_down(cnt0, off); cnt1 += __shfl_down(cnt1, off);
        cnt2 += __shfl_down(cnt2, off); cnt3 += __shfl_down(cnt3, off);
        unsigned u0 = __shfl_down(mn0, off); mn0 = u0 < mn0 ? u0 : mn0;
        unsigned u1 = __shfl_down(mn1, off); mn1 = u1 < mn1 ? u1 : mn1;
        unsigned u2 = __shfl_down(mn2, off); mn2 = u2 < mn2 ? u2 : mn2;
        unsigned u3 = __shfl_down(mn3, off); mn3 = u3 < mn3 ? u3 : mn3;
    }
    if (lane == 0) {
        atomicAdd(&s_cnt[0], cnt0); atomicMin(&s_mn[0], mn0);
        atomicAdd(&s_cnt[1], cnt1); atomicMin(&s_mn[1], mn1);
        atomicAdd(&s_cnt[2], cnt2); atomicMin(&s_mn[2], mn2);
        atomicAdd(&s_cnt[3], cnt3); atomicMin(&s_mn[3], mn3);
    }
    __syncthreads();
    if (tid < 4) {
        const float Qs[4] = {0.05f, 0.95f, 0.25f, 0.75f};
        const float pos = Qs[tid] * (float)(NV - 1);
        const int   k0  = (int)floorf(pos);
        const float fr  = pos - (float)k0;
        const float v0  = k2f(s_prefix[tid]);
        const float v1  = (s_cnt[tid] >= k0 + 2) ? v0 : k2f(s_mn[tid]);
        s_qv[tid] = v0 + fr * (v1 - v0);
    }
    __syncthreads();
    const float q0 = s_qv[0], q1 = s_qv[1], q2 = s_qv[2], q3 = s_qv[3];

    // ---- Phase D: masked two-pass mean/std from LDS keys ----
    float cb = 0.f, sb = 0.f, ce = 0.f, se = 0.f;
    for (int i = tid; i < NV / 4; i += TPB_TAIL) {
        uint4 kv = k4[i];
        const unsigned ks[4] = {kv.x, kv.y, kv.z, kv.w};
        #pragma unroll
        for (int u = 0; u < 4; ++u) {
            const float val = k2f(ks[u]);
            if ((val < q0) || (val > q1)) { cb += 1.f; sb += val; }
            if ((val > q2) && (val < q3)) { ce += 1.f; se += val; }
        }
    }
    #pragma unroll
    for (int off = 32; off > 0; off >>= 1) {
        cb += __shfl_down(cb, off); sb += __shfl_down(sb, off);
        ce += __shfl_down(ce, off); se += __shfl_down(se, off);
    }
    if (lane == 0) {
        red[wid * 4 + 0] = cb; red[wid * 4 + 1] = sb;
        red[wid * 4 + 2] = ce; red[wid * 4 + 3] = se;
    }
    __syncthreads();
    if (tid == 0) {
        float tcb = 0.f, tsb = 0.f, tce = 0.f, tse = 0.f;
        for (int w = 0; w < 16; ++w) {
            tcb += red[w * 4 + 0]; tsb += red[w * 4 + 1];
            tce += red[w * 4 + 2]; tse += red[w * 4 + 3];
        }
        sh[0] = tsb / tcb;  sh[1] = tse / tce;   // means
        sh[2] = tcb;        sh[3] = tce;         // counts
    }
    __syncthreads();
    const float mean_b = sh[0], mean_e = sh[1];
    const float nb = sh[2], ne = sh[3];

    float vb = 0.f, ve = 0.f;
    for (int i = tid; i < NV / 4; i += TPB_TAIL) {
        uint4 kv = k4[i];
        const unsigned ks[4] = {kv.x, kv.y, kv.z, kv.w};
        #pragma unroll
        for (int u = 0; u < 4; ++u) {
            const float val = k2f(ks[u]);
            if ((val < q0) || (val > q1)) { float d = val - mean_b; vb += d * d; }
            if ((val > q2) && (val < q3)) { float d = val - mean_e; ve += d * d; }
        }
    }
    #pragma unroll
    for (int off = 32; off > 0; off >>= 1) {
        vb += __shfl_down(vb, off);
        ve += __shfl_down(ve, off);
    }
    __syncthreads();
    if (lane == 0) { red[wid * 2 + 0] = vb; red[wid * 2 + 1] = ve; }
    __syncthreads();
    if (tid == 0) {
        float tvb = 0.f, tve = 0.f;
        for (int w = 0; w < 16; ++w) { tvb += red[w * 2 + 0]; tve += red[w * 2 + 1]; }
        stats[pair * 2 + 0] = sqrtf(tvb / (nb - 1.f));   // unbiased std, begin
        stats[pair * 2 + 1] = sqrtf(tve / (ne - 1.f));   // unbiased std, end
    }
}

// ---------------------------------------------------------------------------
// Kernel 4: per-batch max over directions, mean over batches.
// ---------------------------------------------------------------------------
__global__ void final_kernel(const float* __restrict__ stats, float* __restrict__ out) {
    if (threadIdx.x == 0 && blockIdx.x == 0) {
        float sb = 0.f, se = 0.f;
        for (int b = 0; b < B_; ++b) {
            float b1 = stats[(b * 2 + 0) * 2 + 0];
            float b2 = stats[(b * 2 + 1) * 2 + 0];
            float e1 = stats[(b * 2 + 0) * 2 + 1];
            float e2 = stats[(b * 2 + 1) * 2 + 1];
            sb += fmaxf(b1, b2);
            se += fmaxf(e1, e2);
        }
        out[0] = sb / (float)B_;
        out[1] = se / (float)B_;
    }
}

template <int NCCH>
static void run_pipeline(const float* x, const float* y, float2* part,
                         unsigned* keys, float* stats, float* out,
                         hipStream_t stream) {
    nn_partial_kernel<NCCH><<<dim3(NCCH, 2, 8), 256, 0, stream>>>(x, y, part);
    merge_keys_kernel<NCCH><<<dim3(N_ / 256, 8), 256, 0, stream>>>(x, y, part, keys);
    tail_kernel<<<8, TPB_TAIL, 0, stream>>>(keys, stats);
    final_kernel<<<1, 64, 0, stream>>>(stats, out);
}

extern "C" void kernel_launch(void* const* d_in, const int* in_sizes, int n_in,
                              void* d_out, int out_size, void* d_ws, size_t ws_size,
                              hipStream_t stream) {
    const float* x = (const float*)d_in[0];
    const float* y = (const float*)d_in[1];
    float* out = (float*)d_out;

    // Workspace: [keys 384KB][stats 64B][part ...]
    unsigned* keys  = (unsigned*)d_ws;
    float*    stats = (float*)(keys + (size_t)8 * NV);
    float2*   part  = (float2*)(stats + 16);

    const size_t head   = ((size_t)8 * NV + 16) * sizeof(float);
    const size_t need64 = head + (size_t)8 * 64 * N_ * sizeof(float2);  // ~17 MB

    if (ws_size >= need64) {
        run_pipeline<64>(x, y, part, keys, stats, out, stream);
    } else {
        run_pipeline<8>(x, y, part, keys, stats, out, stream);
    }
}

// Round 13
// 65.646 us; speedup vs baseline: 1.2288x; 1.2288x over previous
//
#include <hip/hip_runtime.h>
#include <math.h>

// Problem constants (fixed by the reference: B=4, N=4096, D=3)
constexpr int B_  = 4;
constexpr int N_  = 4096;
constexpr int NV  = N_ * 3;      // 12288 flattened residual elements per (batch,dir)
constexpr int NCCH = 16;         // candidate chunks
constexpr int CCH  = N_ / NCCH;  // 256 candidates per chunk
constexpr int TPB_TAIL = 1024;   // tail kernel block size

// float <-> monotonic uint key (order-preserving bijection on finite floats)
__device__ inline unsigned f2k(float f) {
    unsigned b = __float_as_uint(f);
    return b ^ ((unsigned)((int)b >> 31) | 0x80000000u);
}
__device__ inline float k2f(unsigned k) {
    unsigned b = (k & 0x80000000u) ? (k ^ 0x80000000u) : ~k;
    return __uint_as_float(b);
}

// ---------------------------------------------------------------------------
// Kernel 0: prescale candidates: pre[t] = {-2bx,-2by,-2bz,|b|^2}.
// grid = (B_*N_/256, 2): y-dim picks x or y input.
// ---------------------------------------------------------------------------
__global__ __launch_bounds__(256) void prescale_kernel(const float* __restrict__ x,
                                                       const float* __restrict__ y,
                                                       float4* __restrict__ preX,
                                                       float4* __restrict__ preY) {
    const int t = blockIdx.x * 256 + threadIdx.x;        // 0 .. B_*N_-1
    const float* src = blockIdx.y == 0 ? x : y;
    float4* dst      = blockIdx.y == 0 ? preX : preY;
    float bx = src[t * 3 + 0];
    float by = src[t * 3 + 1];
    float bz = src[t * 3 + 2];
    dst[t] = make_float4(-2.f * bx, -2.f * by, -2.f * bz,
                         bx * bx + by * by + bz * bz);
}

// ---------------------------------------------------------------------------
// Kernel 1: partial NN, candidates via SCALAR loads (no LDS in inner loop).
// grid = (NCCH, N_/256 qchunks, 8 pairs) = 2048 blocks = 8 blocks/CU.
// The candidate index (cbase+j) is wave-uniform -> hipcc emits s_load for
// P2[cbase+j] into SGPRs; each inner VALU op reads the candidate as an SGPR
// operand (1 SGPR read/inst, legal). Inner loop = exactly 6 VALU per pair:
// 3 v_fma + v_cmp + v_cndmask + v_min. Zero ds_read, zero lgkm stalls;
// scalar pipe prefetches candidate tiles independently.
// Strict '<' keeps the FIRST minimal index (jnp.argmin tie-break).
// ---------------------------------------------------------------------------
__global__ __launch_bounds__(256) void nn_scalar_kernel(const float* __restrict__ x,
                                                        const float* __restrict__ y,
                                                        const float4* __restrict__ preX,
                                                        const float4* __restrict__ preY,
                                                        float2* __restrict__ part) {
    const int pair = blockIdx.z;
    const int b    = pair >> 1;
    const int dir  = pair & 1;              // 0: S1=x,S2=y ; 1: S1=y,S2=x
    const float*  S1 = (dir == 0 ? x : y) + b * NV;
    const float4* P2 = (dir == 0 ? preY : preX) + b * N_;
    const int cbase = blockIdx.x * CCH;

    const int q = blockIdx.y * 256 + threadIdx.x;
    const float ax = S1[q * 3 + 0];
    const float ay = S1[q * 3 + 1];
    const float az = S1[q * 3 + 2];

    float bd = INFINITY;
    int idx = 0;
    #pragma unroll 16
    for (int j = 0; j < CCH; ++j) {
        const float4 c = P2[cbase + j];     // wave-uniform -> s_load into SGPRs
        // d2 = |b|^2 - 2 a.b  (3 FMAs; candidate components are SGPR operands)
        float d2 = fmaf(ax, c.x, fmaf(ay, c.y, fmaf(az, c.z, c.w)));
        if (d2 < bd) idx = cbase + j;       // v_cmp + v_cndmask (idx src = SGPR)
        bd = fminf(d2, bd);                 // v_min
    }
    part[(size_t)(pair * NCCH + blockIdx.x) * N_ + q] = make_float2(bd, (float)idx);
}

// ---------------------------------------------------------------------------
// Kernel 2: parallel merge. grid = (N_/256, 8 pairs), block = 256.
// NCCH fully unrolled -> independent dwordx2 loads (no latency chain),
// ascending chunk order + strict '<' == global first-index argmin.
// Writes monotonic keys component-major (keys[pair][comp*N+q]) -- fully
// coalesced; quantile/std are order-invariant over the flattened set.
// ---------------------------------------------------------------------------
__global__ __launch_bounds__(256) void merge_keys_kernel(const float* __restrict__ x,
                                                         const float* __restrict__ y,
                                                         const float2* __restrict__ part,
                                                         unsigned* __restrict__ keys) {
    const int pair = blockIdx.y;
    const int b    = pair >> 1;
    const int dir  = pair & 1;
    const float* S1 = (dir == 0 ? x : y) + b * NV;
    const float* S2 = (dir == 0 ? y : x) + b * NV;
    const int q = blockIdx.x * 256 + threadIdx.x;

    float best = INFINITY;
    int bidx = 0;
    #pragma unroll
    for (int c = 0; c < NCCH; ++c) {
        float2 p = part[(size_t)(pair * NCCH + c) * N_ + q];
        if (p.x < best) { best = p.x; bidx = (int)p.y; }
    }
    unsigned* kp = keys + (size_t)pair * NV;
    kp[0 * N_ + q] = f2k(S1[q * 3 + 0] - S2[bidx * 3 + 0]);
    kp[1 * N_ + q] = f2k(S1[q * 3 + 1] - S2[bidx * 3 + 1]);
    kp[2 * N_ + q] = f2k(S1[q * 3 + 2] - S2[bidx * 3 + 2]);
}

// ---------------------------------------------------------------------------
// Kernel 3 (TAIL): one block per (batch,dir) pair, 1024 threads (16 waves).
//   A: stream keys into LDS (3 uint4 loads/thread, coalesced).
//   B: 4x 8-bit MSD radix-select for all four quantile order-stats at once
//      (uint4-vectorized scans; pass-1 hist has 8 wave-group-private copies).
//   C: fused count(<=key0)/min(>key0) -> linear-interp quantiles
//      (positions in fp32, identical to jnp.quantile).
//   D: two-pass masked mean/std from LDS keys (k2f exact inverse).
// ---------------------------------------------------------------------------
__global__ __launch_bounds__(TPB_TAIL) void tail_kernel(const unsigned* __restrict__ gkeys,
                                                        float* __restrict__ stats) {
    __shared__ unsigned keys[NV];           // 48 KB
    __shared__ int hist8[8][256];           // 8 KB
    __shared__ unsigned s_prefix[4];
    __shared__ int s_want[4];
    __shared__ int s_cnt[4];
    __shared__ unsigned s_mn[4];
    __shared__ float s_qv[4];
    __shared__ float red[64];
    __shared__ float sh[8];

    const int pair = blockIdx.x;
    const int tid  = threadIdx.x;
    const int lane = tid & 63;
    const int wid  = tid >> 6;              // 16 waves

    // ---- Phase A: stream keys into LDS ----
    const uint4* g4 = (const uint4*)(gkeys + (size_t)pair * NV);
    uint4* l4w = (uint4*)keys;
    #pragma unroll
    for (int i = 0; i < 3; ++i)             // NV/4 = 3072 = 3 * 1024 exact
        l4w[i * TPB_TAIL + tid] = g4[i * TPB_TAIL + tid];
    if (tid < 4) {
        const float Qs[4] = {0.05f, 0.95f, 0.25f, 0.75f};
        s_prefix[tid] = 0u;
        s_want[tid]   = (int)floorf(Qs[tid] * (float)(NV - 1));
    }
    __syncthreads();

    // ---- Phase B: 4 radix passes (uint4-vectorized element scans) ----
    const uint4* k4 = (const uint4*)keys;
    #pragma unroll 1
    for (int pass = 0; pass < 4; ++pass) {
        const int shift = 24 - 8 * pass;
        ((int*)hist8)[tid]             = 0; // 2048 ints, 2 stores/thread
        ((int*)hist8)[tid + TPB_TAIL]  = 0;
        __syncthreads();

        if (pass == 0) {
            int* h = hist8[wid & 7];        // wave-group-private copy
            for (int i = tid; i < NV / 4; i += TPB_TAIL) {
                uint4 kv = k4[i];
                atomicAdd(&h[kv.x >> 24], 1);
                atomicAdd(&h[kv.y >> 24], 1);
                atomicAdd(&h[kv.z >> 24], 1);
                atomicAdd(&h[kv.w >> 24], 1);
            }
        } else {
            const unsigned pmask = 0xFFFFFFFFu << (32 - 8 * pass);
            const unsigned pf0 = s_prefix[0], pf1 = s_prefix[1];
            const unsigned pf2 = s_prefix[2], pf3 = s_prefix[3];
            for (int i = tid; i < NV / 4; i += TPB_TAIL) {
                uint4 kv = k4[i];
                const unsigned ks[4] = {kv.x, kv.y, kv.z, kv.w};
                #pragma unroll
                for (int u = 0; u < 4; ++u) {
                    const unsigned k  = ks[u];
                    const unsigned kp = k & pmask;
                    const int bin = (int)((k >> shift) & 255u);
                    if (kp == pf0) atomicAdd(&hist8[0][bin], 1);
                    if (kp == pf1) atomicAdd(&hist8[1][bin], 1);
                    if (kp == pf2) atomicAdd(&hist8[2][bin], 1);
                    if (kp == pf3) atomicAdd(&hist8[3][bin], 1);
                }
            }
        }
        __syncthreads();

        // selection: wave t (t<4) scans quantile t's histogram
        if (wid < 4) {
            int c0 = 0, c1 = 0, c2 = 0, c3 = 0;
            if (pass == 0) {
                #pragma unroll
                for (int cp = 0; cp < 8; ++cp) {
                    c0 += hist8[cp][lane * 4 + 0]; c1 += hist8[cp][lane * 4 + 1];
                    c2 += hist8[cp][lane * 4 + 2]; c3 += hist8[cp][lane * 4 + 3];
                }
            } else {
                c0 = hist8[wid][lane * 4 + 0]; c1 = hist8[wid][lane * 4 + 1];
                c2 = hist8[wid][lane * 4 + 2]; c3 = hist8[wid][lane * 4 + 3];
            }
            const int want = s_want[wid];
            int s = c0 + c1 + c2 + c3;
            int pre = s;
            #pragma unroll
            for (int off = 1; off < 64; off <<= 1) {
                int u = __shfl_up(pre, off);
                if (lane >= off) pre += u;
            }
            const int excl = pre - s;
            const bool hit = (want >= excl) && (want < excl + s);
            unsigned long long m = __ballot(hit);
            const int hl = (int)(__ffsll(m) - 1);
            if (lane == hl) {
                int w = want - excl;
                int sel;
                if      (w < c0)           { sel = lane * 4 + 0; }
                else if (w < c0 + c1)      { sel = lane * 4 + 1; w -= c0; }
                else if (w < c0 + c1 + c2) { sel = lane * 4 + 2; w -= c0 + c1; }
                else                       { sel = lane * 4 + 3; w -= c0 + c1 + c2; }
                s_prefix[wid] |= ((unsigned)sel) << shift;
                s_want[wid] = w;
            }
        }
        __syncthreads();
    }

    // ---- Phase C: count(<=key0) and min(>key0) for all 4 quantiles ----
    if (tid < 4) { s_cnt[tid] = 0; s_mn[tid] = 0xFFFFFFFFu; }
    __syncthreads();
    const unsigned kq0 = s_prefix[0], kq1 = s_prefix[1];
    const unsigned kq2 = s_prefix[2], kq3 = s_prefix[3];
    int cnt0 = 0, cnt1 = 0, cnt2 = 0, cnt3 = 0;
    unsigned mn0 = 0xFFFFFFFFu, mn1 = 0xFFFFFFFFu, mn2 = 0xFFFFFFFFu, mn3 = 0xFFFFFFFFu;
    for (int i = tid; i < NV / 4; i += TPB_TAIL) {
        uint4 kv = k4[i];
        const unsigned ks[4] = {kv.x, kv.y, kv.z, kv.w};
        #pragma unroll
        for (int u = 0; u < 4; ++u) {
            const unsigned k = ks[u];
            if (k <= kq0) cnt0++; else if (k < mn0) mn0 = k;
            if (k <= kq1) cnt1++; else if (k < mn1) mn1 = k;
            if (k <= kq2) cnt2++; else if (k < mn2) mn2 = k;
            if (k <= kq3) cnt3++; else if (k < mn3) mn3 = k;
        }
    }
    #pragma unroll
    for (int off = 32; off > 0; off >>= 1) {
        cnt0 += __shfl_down(cnt0, off); cnt1 += __shfl_down(cnt1, off);
        cnt2 += __shfl_down(cnt2, off); cnt3 += __shfl_down(cnt3, off);
        unsigned u0 = __shfl_down(mn0, off); mn0 = u0 < mn0 ? u0 : mn0;
        unsigned u1 = __shfl_down(mn1, off); mn1 = u1 < mn1 ? u1 : mn1;
        unsigned u2 = __shfl_down(mn2, off); mn2 = u2 < mn2 ? u2 : mn2;
        unsigned u3 = __shfl_down(mn3, off); mn3 = u3 < mn3 ? u3 : mn3;
    }
    if (lane == 0) {
        atomicAdd(&s_cnt[0], cnt0); atomicMin(&s_mn[0], mn0);
        atomicAdd(&s_cnt[1], cnt1); atomicMin(&s_mn[1], mn1);
        atomicAdd(&s_cnt[2], cnt2); atomicMin(&s_mn[2], mn2);
        atomicAdd(&s_cnt[3], cnt3); atomicMin(&s_mn[3], mn3);
    }
    __syncthreads();
    if (tid < 4) {
        const float Qs[4] = {0.05f, 0.95f, 0.25f, 0.75f};
        const float pos = Qs[tid] * (float)(NV - 1);
        const int   k0  = (int)floorf(pos);
        const float fr  = pos - (float)k0;
        const float v0  = k2f(s_prefix[tid]);
        const float v1  = (s_cnt[tid] >= k0 + 2) ? v0 : k2f(s_mn[tid]);
        s_qv[tid] = v0 + fr * (v1 - v0);
    }
    __syncthreads();
    const float q0 = s_qv[0], q1 = s_qv[1], q2 = s_qv[2], q3 = s_qv[3];

    // ---- Phase D: masked two-pass mean/std from LDS keys ----
    float cb = 0.f, sb = 0.f, ce = 0.f, se = 0.f;
    for (int i = tid; i < NV / 4; i += TPB_TAIL) {
        uint4 kv = k4[i];
        const unsigned ks[4] = {kv.x, kv.y, kv.z, kv.w};
        #pragma unroll
        for (int u = 0; u < 4; ++u) {
            const float val = k2f(ks[u]);
            if ((val < q0) || (val > q1)) { cb += 1.f; sb += val; }
            if ((val > q2) && (val < q3)) { ce += 1.f; se += val; }
        }
    }
    #pragma unroll
    for (int off = 32; off > 0; off >>= 1) {
        cb += __shfl_down(cb, off); sb += __shfl_down(sb, off);
        ce += __shfl_down(ce, off); se += __shfl_down(se, off);
    }
    if (lane == 0) {
        red[wid * 4 + 0] = cb; red[wid * 4 + 1] = sb;
        red[wid * 4 + 2] = ce; red[wid * 4 + 3] = se;
    }
    __syncthreads();
    if (tid == 0) {
        float tcb = 0.f, tsb = 0.f, tce = 0.f, tse = 0.f;
        for (int w = 0; w < 16; ++w) {
            tcb += red[w * 4 + 0]; tsb += red[w * 4 + 1];
            tce += red[w * 4 + 2]; tse += red[w * 4 + 3];
        }
        sh[0] = tsb / tcb;  sh[1] = tse / tce;   // means
        sh[2] = tcb;        sh[3] = tce;         // counts
    }
    __syncthreads();
    const float mean_b = sh[0], mean_e = sh[1];
    const float nb = sh[2], ne = sh[3];

    float vb = 0.f, ve = 0.f;
    for (int i = tid; i < NV / 4; i += TPB_TAIL) {
        uint4 kv = k4[i];
        const unsigned ks[4] = {kv.x, kv.y, kv.z, kv.w};
        #pragma unroll
        for (int u = 0; u < 4; ++u) {
            const float val = k2f(ks[u]);
            if ((val < q0) || (val > q1)) { float d = val - mean_b; vb += d * d; }
            if ((val > q2) && (val < q3)) { float d = val - mean_e; ve += d * d; }
        }
    }
    #pragma unroll
    for (int off = 32; off > 0; off >>= 1) {
        vb += __shfl_down(vb, off);
        ve += __shfl_down(ve, off);
    }
    __syncthreads();
    if (lane == 0) { red[wid * 2 + 0] = vb; red[wid * 2 + 1] = ve; }
    __syncthreads();
    if (tid == 0) {
        float tvb = 0.f, tve = 0.f;
        for (int w = 0; w < 16; ++w) { tvb += red[w * 2 + 0]; tve += red[w * 2 + 1]; }
        stats[pair * 2 + 0] = sqrtf(tvb / (nb - 1.f));   // unbiased std, begin
        stats[pair * 2 + 1] = sqrtf(tve / (ne - 1.f));   // unbiased std, end
    }
}

// ---------------------------------------------------------------------------
// Kernel 4: per-batch max over directions, mean over batches.
// ---------------------------------------------------------------------------
__global__ void final_kernel(const float* __restrict__ stats, float* __restrict__ out) {
    if (threadIdx.x == 0 && blockIdx.x == 0) {
        float sb = 0.f, se = 0.f;
        for (int b = 0; b < B_; ++b) {
            float b1 = stats[(b * 2 + 0) * 2 + 0];
            float b2 = stats[(b * 2 + 1) * 2 + 0];
            float e1 = stats[(b * 2 + 0) * 2 + 1];
            float e2 = stats[(b * 2 + 1) * 2 + 1];
            sb += fmaxf(b1, b2);
            se += fmaxf(e1, e2);
        }
        out[0] = sb / (float)B_;
        out[1] = se / (float)B_;
    }
}

extern "C" void kernel_launch(void* const* d_in, const int* in_sizes, int n_in,
                              void* d_out, int out_size, void* d_ws, size_t ws_size,
                              hipStream_t stream) {
    const float* x = (const float*)d_in[0];
    const float* y = (const float*)d_in[1];
    float* out = (float*)d_out;

    // Workspace layout:
    // [keys 384KB][stats 16f][pad][preX 256KB][preY 256KB][part 4MB]
    unsigned* keys  = (unsigned*)d_ws;
    float*    stats = (float*)(keys + (size_t)8 * NV);
    float4*   preX  = (float4*)(stats + 16);
    float4*   preY  = preX + (size_t)B_ * N_;
    float2*   part  = (float2*)(preY + (size_t)B_ * N_);

    prescale_kernel<<<dim3(B_ * N_ / 256, 2), 256, 0, stream>>>(x, y, preX, preY);
    nn_scalar_kernel<<<dim3(NCCH, N_ / 256, 8), 256, 0, stream>>>(x, y, preX, preY, part);
    merge_keys_kernel<<<dim3(N_ / 256, 8), 256, 0, stream>>>(x, y, part, keys);
    tail_kernel<<<8, TPB_TAIL, 0, stream>>>(keys, stats);
    final_kernel<<<1, 64, 0, stream>>>(stats, out);
}